// Round 4
// baseline (994.012 us; speedup 1.0000x reference)
//
#include <hip/hip_runtime.h>
#include <hip/hip_bf16.h>
#include <float.h>

#define HEADS 4
#define DK 32

static constexpr float kBeta = 1.0f;
static constexpr float kNeg  = 0.2f;
static constexpr float kEps  = 1e-12f;

__device__ __forceinline__ float bf2f(unsigned short v) {
  return __uint_as_float((unsigned)v << 16);
}
__device__ __forceinline__ float2 bfp2(unsigned u) {
  return make_float2(__uint_as_float(u << 16), __uint_as_float(u & 0xFFFF0000u));
}
// order-preserving float <-> uint key for atomicMax
__device__ __forceinline__ unsigned fkey(float x) {
  unsigned u = __float_as_uint(x);
  return (u & 0x80000000u) ? ~u : (u | 0x80000000u);
}
__device__ __forceinline__ float funkey(unsigned k) {
  unsigned u = (k & 0x80000000u) ? (k & 0x7fffffffu) : ~k;
  return __uint_as_float(u);
}

// ---- K0a: edge layout detect (int64 -> odd words all 0) ----------------------
__global__ __launch_bounds__(256) void k_detect_edges(const int* __restrict__ ei32,
                                                      int* __restrict__ eflag, int E) {
  int i = blockIdx.x * 256 + threadIdx.x;  // [0, 4096)
  if (2 * i + 1 < 2 * E && ei32[2 * i + 1] != 0) atomicOr(eflag, 1);
}

// ---- K0b: float dtype detect: fp32 words have random mantissa bits 14..7 -----
// (w>>7)&0xFF==0xFF fires ~1/256 on fp32 N(0,1); impossible for finite bf16 pairs.
__global__ __launch_bounds__(256) void k_detect_dtype(const unsigned* __restrict__ Hw,
                                                      int* __restrict__ dflag, int nw) {
  int i = blockIdx.x * 256 + threadIdx.x;
  if (i < nw && ((Hw[i] >> 7) & 0xFFu) == 0xFFu) atomicOr(dflag, 1);
}

// ---- K0c: normalize edge index into int32 src/dst ----------------------------
__global__ __launch_bounds__(256) void k_cvt(const int* __restrict__ ei32,
                                             const int* __restrict__ eflag,
                                             int* __restrict__ src_i,
                                             int* __restrict__ dst_i, int E) {
  int i = blockIdx.x * 256 + threadIdx.x;
  if (i >= E) return;
  if (*eflag) { src_i[i] = ei32[i];     dst_i[i] = ei32[E + i]; }
  else        { src_i[i] = ei32[2 * i]; dst_i[i] = ei32[2 * E + 2 * i]; }
}

// ---- K0d: param convert to fp32 (identity copy if already fp32) --------------
__global__ __launch_bounds__(256) void k_f32cvt(const void* __restrict__ in,
                                                float* __restrict__ out,
                                                const int* __restrict__ dflag, int n) {
  int i = blockIdx.x * 256 + threadIdx.x;
  if (i >= n) return;
  out[i] = (*dflag) ? ((const float*)in)[i] : bf2f(((const unsigned short*)in)[i]);
}

// ---- K1: H_proj = H @ W.T (dual-dtype H staging; W pre-converted fp32) -------
__global__ __launch_bounds__(256) void k_proj(const void* __restrict__ Hraw,
                                              const float* __restrict__ Wf,
                                              const int* __restrict__ dflag,
                                              float* __restrict__ Hproj, int N) {
  __shared__ float Ht[32][260];
  const int t = threadIdx.x;
  const int nb = blockIdx.x * 32;
  const int dt = *dflag;
  if (dt) {  // fp32 input
    const float4* __restrict__ H4 = (const float4*)Hraw;
#pragma unroll
    for (int i = 0; i < 8; ++i) {
      int f = t + i * 256;
      int r = f >> 6, kq = f & 63;
      float4 v = make_float4(0.f, 0.f, 0.f, 0.f);
      if (nb + r < N) v = H4[(size_t)(nb + r) * 64 + kq];
      *(float4*)&Ht[r][4 * kq] = v;
    }
  } else {   // bf16 input
    const uint4* __restrict__ H8 = (const uint4*)Hraw;
#pragma unroll
    for (int i = 0; i < 4; ++i) {
      int g = t + i * 256;
      int r = g >> 5, c8 = g & 31;
      uint4 v = make_uint4(0u, 0u, 0u, 0u);
      if (nb + r < N) v = H8[(size_t)(nb + r) * 32 + c8];
      float2 f0 = bfp2(v.x), f1 = bfp2(v.y), f2 = bfp2(v.z), f3 = bfp2(v.w);
      *(float4*)&Ht[r][c8 * 8 + 0] = make_float4(f0.x, f0.y, f1.x, f1.y);
      *(float4*)&Ht[r][c8 * 8 + 4] = make_float4(f2.x, f2.y, f3.x, f3.y);
    }
  }
  __syncthreads();
  const int c0 = (t & 31) * 4;
  const int n0 = (t >> 5) * 4;
  float acc[4][4];
#pragma unroll
  for (int n = 0; n < 4; ++n)
#pragma unroll
    for (int j = 0; j < 4; ++j) acc[n][j] = 0.f;
  const float4* __restrict__ W4 = (const float4*)Wf;
#pragma unroll 4
  for (int kq = 0; kq < 64; ++kq) {
    float4 w0 = W4[(size_t)(c0 + 0) * 64 + kq];
    float4 w1 = W4[(size_t)(c0 + 1) * 64 + kq];
    float4 w2 = W4[(size_t)(c0 + 2) * 64 + kq];
    float4 w3 = W4[(size_t)(c0 + 3) * 64 + kq];
#pragma unroll
    for (int n = 0; n < 4; ++n) {
      float4 h = *(const float4*)&Ht[n0 + n][4 * kq];
      acc[n][0] += h.x * w0.x + h.y * w0.y + h.z * w0.z + h.w * w0.w;
      acc[n][1] += h.x * w1.x + h.y * w1.y + h.z * w1.z + h.w * w1.w;
      acc[n][2] += h.x * w2.x + h.y * w2.y + h.z * w2.z + h.w * w2.w;
      acc[n][3] += h.x * w3.x + h.y * w3.y + h.z * w3.z + h.w * w3.w;
    }
  }
#pragma unroll
  for (int n = 0; n < 4; ++n) {
    int row = nb + n0 + n;
    if (row < N)
      *(float4*)&Hproj[(size_t)row * 128 + c0] =
          make_float4(acc[n][0], acc[n][1], acc[n][2], acc[n][3]);
  }
}

// ---- K2: per-node attention dots + msg base ----------------------------------
__global__ __launch_bounds__(256) void k_node(const float* __restrict__ Hproj,
                                              const float* __restrict__ af,   // [a_src(128)|a_dst(128)]
                                              const float* __restrict__ msgwf,
                                              float* __restrict__ s_src,
                                              float* __restrict__ s_dst,
                                              float* __restrict__ msgb, int N) {
  const int l = threadIdx.x & 63;
  const int wb = threadIdx.x >> 6;
  const int n = (blockIdx.x << 2) + wb;
  if (n >= N) return;
  const float* row = Hproj + (size_t)n * 128;
  float h0 = row[l], h1 = row[64 + l];
  float p0 = h0 * af[l],       p1 = h1 * af[64 + l];
  float q0 = h0 * af[128 + l], q1 = h1 * af[192 + l];
#pragma unroll
  for (int off = 16; off; off >>= 1) {
    p0 += __shfl_xor(p0, off);
    p1 += __shfl_xor(p1, off);
    q0 += __shfl_xor(q0, off);
    q1 += __shfl_xor(q1, off);
  }
  if (l == 0)  { s_src[n*4+0] = p0; s_src[n*4+2] = p1; s_dst[n*4+0] = q0; s_dst[n*4+2] = q1; }
  if (l == 32) { s_src[n*4+1] = p0; s_src[n*4+3] = p1; s_dst[n*4+1] = q0; s_dst[n*4+3] = q1; }
  float t4 = h0 + __shfl_xor(h0, 32) + h1 + __shfl_xor(h1, 32);
  float hbar = 0.25f * t4;  // lanes 0..31: mean over heads at d=l
  if (l < DK) {
    float acc = 0.f;
#pragma unroll
    for (int d = 0; d < DK; ++d) acc += __shfl(hbar, d) * msgwf[l * DK + d];
    msgb[(size_t)n * DK + l] = acc;
  }
}

// ---- K3: per-edge logits + LeakyReLU + per-head global max -------------------
__global__ __launch_bounds__(256) void k_logits(const int* __restrict__ src,
                                                const int* __restrict__ dst,
                                                const void* __restrict__ sim1,
                                                const int* __restrict__ dflag,
                                                const float* __restrict__ s_src,
                                                const float* __restrict__ s_dst,
                                                float4* __restrict__ e_vals,
                                                unsigned* __restrict__ gmax, int E) {
  const int e = blockIdx.x * 256 + threadIdx.x;
  float m0 = -FLT_MAX, m1 = -FLT_MAX, m2 = -FLT_MAX, m3 = -FLT_MAX;
  if (e < E) {
    int s = src[e], d = dst[e];
    float4 ss = *(const float4*)(s_src + (size_t)s * 4);
    float4 sd = *(const float4*)(s_dst + (size_t)d * 4);
    float sv = (*dflag) ? ((const float*)sim1)[e] : bf2f(((const unsigned short*)sim1)[e]);
    float b = kBeta * sv;
    float e0 = ss.x + sd.x + b; e0 = (e0 >= 0.f) ? e0 : kNeg * e0;
    float e1 = ss.y + sd.y + b; e1 = (e1 >= 0.f) ? e1 : kNeg * e1;
    float e2 = ss.z + sd.z + b; e2 = (e2 >= 0.f) ? e2 : kNeg * e2;
    float e3 = ss.w + sd.w + b; e3 = (e3 >= 0.f) ? e3 : kNeg * e3;
    e_vals[e] = make_float4(e0, e1, e2, e3);
    m0 = e0; m1 = e1; m2 = e2; m3 = e3;
  }
#pragma unroll
  for (int off = 32; off; off >>= 1) {
    m0 = fmaxf(m0, __shfl_xor(m0, off));
    m1 = fmaxf(m1, __shfl_xor(m1, off));
    m2 = fmaxf(m2, __shfl_xor(m2, off));
    m3 = fmaxf(m3, __shfl_xor(m3, off));
  }
  __shared__ float red[4][4];
  if ((threadIdx.x & 63) == 0) {
    int w = threadIdx.x >> 6;
    red[w][0] = m0; red[w][1] = m1; red[w][2] = m2; red[w][3] = m3;
  }
  __syncthreads();
  if (threadIdx.x < 4) {
    int h = threadIdx.x;
    float mm = fmaxf(fmaxf(red[0][h], red[1][h]), fmaxf(red[2][h], red[3][h]));
    atomicMax(gmax + h, fkey(mm));
  }
}

// ---- K4: exp(e - max) + denom segment-sum ------------------------------------
__global__ __launch_bounds__(256) void k_exp(const int* __restrict__ dst,
                                             float4* __restrict__ e_vals,
                                             const unsigned* __restrict__ gmax,
                                             float* __restrict__ denom, int E) {
  const int e = blockIdx.x * 256 + threadIdx.x;
  if (e >= E) return;
  float m0 = funkey(gmax[0]), m1 = funkey(gmax[1]);
  float m2 = funkey(gmax[2]), m3 = funkey(gmax[3]);
  float4 v = e_vals[e];
  v.x = expf(v.x - m0); v.y = expf(v.y - m1);
  v.z = expf(v.z - m2); v.w = expf(v.w - m3);
  e_vals[e] = v;
  int d = dst[e];
  atomicAdd(denom + (size_t)d * 4 + 0, v.x);
  atomicAdd(denom + (size_t)d * 4 + 1, v.y);
  atomicAdd(denom + (size_t)d * 4 + 2, v.z);
  atomicAdd(denom + (size_t)d * 4 + 3, v.w);
}

// ---- K5: wave-per-edge: alpha_mean, msg_base, out_h scatter ------------------
__global__ __launch_bounds__(256) void k_scatter(const int* __restrict__ src,
                                                 const int* __restrict__ dst,
                                                 const float4* __restrict__ e_vals,
                                                 const float* __restrict__ denom,
                                                 const float* __restrict__ msgb,
                                                 const float* __restrict__ Hproj,
                                                 const int* __restrict__ dflag,
                                                 float* __restrict__ out_acc,
                                                 void* __restrict__ d_out,
                                                 int N, int E) {
  const int wid = (int)((blockIdx.x * 256 + threadIdx.x) >> 6);
  const int l = threadIdx.x & 63;
  if (wid >= E) return;
  const int dt = *dflag;
  const int s = src[wid], d = dst[wid];
  float4 ex = e_vals[wid];
  float4 dn = *(const float4*)(denom + (size_t)d * 4);
  float a0 = ex.x / (dn.x + kEps);
  float a1 = ex.y / (dn.y + kEps);
  float a2 = ex.z / (dn.z + kEps);
  float a3 = ex.w / (dn.w + kEps);
  const size_t alpha_off = (size_t)N * 128;
  const size_t msg_off   = alpha_off + (size_t)E;
  if (l == 0) {
    float am = 0.25f * (a0 + a1 + a2 + a3);
    if (dt) ((float*)d_out)[alpha_off + wid] = am;
    else    ((__hip_bfloat16*)d_out)[alpha_off + wid] = __float2bfloat16(am);
  }
  if (l < DK) {
    float mv = msgb[(size_t)s * DK + l];
    if (dt) ((float*)d_out)[msg_off + (size_t)wid * DK + l] = mv;
    else    ((__hip_bfloat16*)d_out)[msg_off + (size_t)wid * DK + l] = __float2bfloat16(mv);
  }
  float h_lo = Hproj[(size_t)s * 128 + l];
  float h_hi = Hproj[(size_t)s * 128 + 64 + l];
  float a_lo = (l < 32) ? a0 : a1;   // head(col l) = l>>5
  float a_hi = (l < 32) ? a2 : a3;   // head(col 64+l) = 2+(l>>5)
  atomicAdd(out_acc + (size_t)d * 128 + l,      a_lo * h_lo);
  atomicAdd(out_acc + (size_t)d * 128 + 64 + l, a_hi * h_hi);
}

// ---- K6: out_acc (fp32) -> out_h (fp32 or bf16) ------------------------------
__global__ __launch_bounds__(256) void k_finalize(const float4* __restrict__ out_acc,
                                                  void* __restrict__ d_out,
                                                  const int* __restrict__ dflag, int n4) {
  int i = blockIdx.x * 256 + threadIdx.x;
  if (i >= n4) return;
  float4 v = out_acc[i];
  if (*dflag) {
    ((float4*)d_out)[i] = v;
  } else {
    __hip_bfloat162* o = (__hip_bfloat162*)d_out;
    o[i * 2 + 0] = __float22bfloat162_rn(make_float2(v.x, v.y));
    o[i * 2 + 1] = __float22bfloat162_rn(make_float2(v.z, v.w));
  }
}

extern "C" void kernel_launch(void* const* d_in, const int* in_sizes, int n_in,
                              void* d_out, int out_size, void* d_ws, size_t ws_size,
                              hipStream_t stream) {
  const void* H     = d_in[0];
  const int*  ei    = (const int*)d_in[1];
  const void* sim1  = d_in[2];
  const void* W     = d_in[3];
  const void* a_src = d_in[4];
  const void* a_dst = d_in[5];
  const void* msg_w = d_in[6];
  const int N = in_sizes[0] / 256;
  const int E = in_sizes[2];

  float* ws      = (float*)d_ws;
  float* Hproj   = ws;                          // N*128
  float* s_src   = Hproj  + (size_t)N * 128;    // N*4
  float* s_dst   = s_src  + (size_t)N * 4;      // N*4
  float* msgb    = s_dst  + (size_t)N * 4;      // N*32
  float* e_vals  = msgb   + (size_t)N * 32;     // E*4
  float* denom   = e_vals + (size_t)E * 4;      // N*4   (zeroed from here)
  float* out_acc = denom  + (size_t)N * 4;      // N*128
  unsigned* gmax = (unsigned*)(out_acc + (size_t)N * 128);  // 4
  int* eflag     = (int*)(gmax + 4);
  int* dflag     = eflag + 1;
  int* src_i     = (int*)(gmax + 8);            // E
  int* dst_i     = src_i + E;                   // E
  float* Wf      = (float*)(dst_i + E);         // 128*256
  float* af      = Wf + 128 * 256;              // 256: [a_src|a_dst]
  float* msgwf   = af + 256;                    // 1024

  size_t zero_bytes = ((size_t)N * 132) * sizeof(float) + 32;  // denom..dflag
  hipMemsetAsync(denom, 0, zero_bytes, stream);

  k_detect_edges<<<16, 256, 0, stream>>>(ei, eflag, E);
  k_detect_dtype<<<512, 256, 0, stream>>>((const unsigned*)H, dflag, 131072);
  k_cvt<<<(E + 255) / 256, 256, 0, stream>>>(ei, eflag, src_i, dst_i, E);
  k_f32cvt<<<128, 256, 0, stream>>>(W, Wf, dflag, 128 * 256);
  k_f32cvt<<<1, 256, 0, stream>>>(a_src, af, dflag, 128);
  k_f32cvt<<<1, 256, 0, stream>>>(a_dst, af + 128, dflag, 128);
  k_f32cvt<<<4, 256, 0, stream>>>(msg_w, msgwf, dflag, 1024);
  k_proj<<<(N + 31) / 32, 256, 0, stream>>>(H, Wf, dflag, Hproj, N);
  k_node<<<(N + 3) / 4, 256, 0, stream>>>(Hproj, af, msgwf, s_src, s_dst, msgb, N);
  k_logits<<<(E + 255) / 256, 256, 0, stream>>>(src_i, dst_i, sim1, dflag, s_src, s_dst,
                                                (float4*)e_vals, gmax, E);
  k_exp<<<(E + 255) / 256, 256, 0, stream>>>(dst_i, (float4*)e_vals, gmax, denom, E);
  k_scatter<<<(int)(((size_t)E * 64 + 255) / 256), 256, 0, stream>>>(
      src_i, dst_i, (const float4*)e_vals, denom, msgb, Hproj, dflag, out_acc, d_out, N, E);
  k_finalize<<<(N * 32 + 255) / 256, 256, 0, stream>>>((const float4*)out_acc, d_out,
                                                       dflag, N * 32);
}